// Round 8
// baseline (224.868 us; speedup 1.0000x reference)
//
#include <hip/hip_runtime.h>

#define NTOK 4096
#define DIMC 1024
#define HEADS 12
#define DH 8
#define QSCALE 0.35355339059327373f   /* 8^-0.5 */
#define LOG2E  1.4426950408889634f
#define LN2    0.6931471805599453f
#define QPRE   (QSCALE * LOG2E)       /* fold log2e into q prescale */

typedef float f4 __attribute__((ext_vector_type(4)));
typedef float f2 __attribute__((ext_vector_type(2)));

// ws layout (floats):
//   Q:  [h][n][8]        (pre-scaled by QPRE), offset 0,    12*4096*8
//   K:  [h][16][8][256]  chunk-tiled SoA,      offset KOFF, 12*8*4096
#define KOFF (HEADS * NTOK * DH)

// ---------------- Kernel 1: proj = x @ W^T -> q (AoS, scaled), k (tiled) ---
__global__ __launch_bounds__(256) void k1_proj(const float* __restrict__ x,
                                               const float* __restrict__ W,
                                               float* __restrict__ qk) {
    __shared__ float xs[8 * 1028];         // pad 1024->1028 breaks bank aliasing
    const int t = threadIdx.x;
    const int row0 = blockIdx.x * 8;

    const f4* x4 = (const f4*)(x + (size_t)row0 * DIMC);
    #pragma unroll
    for (int i = 0; i < 8; ++i) {
        int f = t + i * 256;
        int r = f >> 8;
        int c4 = f & 255;
        f4 v = x4[f];
        *(f4*)(&xs[r * 1028 + c4 * 4]) = v;
    }
    __syncthreads();

    const int g  = t >> 2;                 // 0..63 -> owns o = 3g..3g+2
    const int rg = t & 3;                  // owns rows rg*2 .. rg*2+1

    f2 acc[2][3];
    #pragma unroll
    for (int a = 0; a < 2; ++a)
        #pragma unroll
        for (int m = 0; m < 3; ++m) acc[a][m] = (f2)(0.f);

    const float* w0 = W + (size_t)(3 * g) * DIMC;
    #pragma unroll 2
    for (int c = 0; c < DIMC; c += 4) {
        f4 w[3];
        #pragma unroll
        for (int m = 0; m < 3; ++m)
            w[m] = *(const f4*)(w0 + (size_t)m * DIMC + c);
        #pragma unroll
        for (int a = 0; a < 2; ++a) {
            f4 xv = *(const f4*)(&xs[(rg * 2 + a) * 1028 + c]);
            #pragma unroll
            for (int m = 0; m < 3; ++m) {
                acc[a][m] = __builtin_elementwise_fma(xv.xy, w[m].xy, acc[a][m]);
                acc[a][m] = __builtin_elementwise_fma(xv.zw, w[m].zw, acc[a][m]);
            }
        }
    }

    #pragma unroll
    for (int m = 0; m < 3; ++m) {
        int o   = 3 * g + m;
        int qkf = (o >= 96) ? 1 : 0;
        int oo  = o - 96 * qkf;
        int h   = oo >> 3;
        int d   = oo & 7;
        #pragma unroll
        for (int a = 0; a < 2; ++a) {
            int n = row0 + rg * 2 + a;
            float v = acc[a][m].x + acc[a][m].y;
            if (!qkf) {
                qk[((size_t)h * NTOK + n) * DH + d] = v * QPRE;        // Q AoS
            } else {
                qk[KOFF + (((size_t)h * 16 + (n >> 8)) * DH + d) * 256 + (n & 255)] = v;
            }
        }
    }
}

// ---------------- Kernel 0: zero-fill strictly-upper 256-aligned tiles -----
// grid (16, 64, 12): x=chunk cc, y=64-row block, z=head. Live iff cc > band.
__global__ __launch_bounds__(256) void k_zero(float* __restrict__ out) {
    const int cc = blockIdx.x;
    const int yb = blockIdx.y;
    const int h  = blockIdx.z;
    if (cc <= (yb >> 2)) return;           // band = (yb*64)>>8 = yb>>2
    const int t = threadIdx.x;
    float* base = out + ((size_t)h * NTOK + yb * 64) * NTOK + cc * 256;
    f4 z = (f4)(0.f);
    #pragma unroll
    for (int i = 0; i < 16; ++i) {
        int p = t + i * 256;               // 0..4095 f4-slots in 64x256 tile
        int r = p >> 6;
        int c = p & 63;
        *(f4*)(base + (size_t)r * NTOK + c * 4) = z;   // plain store (memset clone)
    }
}

// ---------------- Kernel 2: computed chunks only, issue-early prefetch -----
__device__ __forceinline__ float lsig2(float u) {
    // logsigmoid in log2 units: min(u,0) - log2(1 + 2^-|u|)   (u = s*log2e)
    float mn = fminf(u, 0.f);
    float z  = __builtin_amdgcn_exp2f(-fabsf(u));   // -|u| is a free modifier
    return mn - __builtin_amdgcn_logf(1.f + z);     // v_log_f32 = log2
}

__global__ __launch_bounds__(256) void k2_gates(const float* __restrict__ qk,
                                                float* __restrict__ out) {
    const int bid  = blockIdx.x;
    const int h    = bid >> 9;              // 512 blocks per head
    const int i0   = (bid & 511) << 3;      // 8 rows per block
    const int t    = threadIdx.x;
    const int lane = t & 63;
    const int wid  = t >> 6;
    const int r0   = i0 + 2 * wid;          // this wave owns rows r0, r0+1
    const int r1   = r0 + 1;

    const float* qrow = qk + ((size_t)h * NTOK + r0) * DH;
    f2 q0s[8], q1s[8];
    #pragma unroll
    for (int d = 0; d < 8; ++d) {
        q0s[d] = (f2)(qrow[d]);
        q1s[d] = (f2)(qrow[DH + d]);
    }

    const float* kh = qk + KOFF + (size_t)h * (16 * DH * 256) + 4 * lane;
    float* o0 = out + ((size_t)h * NTOK + r0) * NTOK;
    float* o1 = o0 + NTOK;

    const int cb = r0 >> 8;                 // boundary chunk (holds j ~ r0)

    float carry0, carry1;

    // initial load: boundary chunk
    f4 kv[8];
    {
        const float* kc = kh + (size_t)cb * (DH * 256);
        #pragma unroll
        for (int d = 0; d < 8; ++d) kv[d] = *(const f4*)(kc + d * 256);
    }

    // ---- boundary chunk cc = cb: masked compute, prefetch cb-1 -------------
    {
        const int j0 = cb * 256 + 4 * lane;

        f2 A0 = (f2)(0.f), B0 = (f2)(0.f), A1 = (f2)(0.f), B1 = (f2)(0.f);
        #pragma unroll
        for (int d = 0; d < 8; ++d) {
            A0 = __builtin_elementwise_fma(kv[d].xy, q0s[d], A0);
            B0 = __builtin_elementwise_fma(kv[d].zw, q0s[d], B0);
            A1 = __builtin_elementwise_fma(kv[d].xy, q1s[d], A1);
            B1 = __builtin_elementwise_fma(kv[d].zw, q1s[d], B1);
        }

        // kv dead -> issue next chunk's loads now (clamped), hide under scan
        {
            const int cn = (cb > 0) ? (cb - 1) : 0;
            const float* kn = kh + (size_t)cn * (DH * 256);
            #pragma unroll
            for (int d = 0; d < 8; ++d) kv[d] = *(const f4*)(kn + d * 256);
        }

        float g0[4], g1[4];
        g0[0] = (j0 + 0 < r0) ? lsig2(A0.x) : 0.f;
        g0[1] = (j0 + 1 < r0) ? lsig2(A0.y) : 0.f;
        g0[2] = (j0 + 2 < r0) ? lsig2(B0.x) : 0.f;
        g0[3] = (j0 + 3 < r0) ? lsig2(B0.y) : 0.f;
        g1[0] = (j0 + 0 < r1) ? lsig2(A1.x) : 0.f;
        g1[1] = (j0 + 1 < r1) ? lsig2(A1.y) : 0.f;
        g1[2] = (j0 + 2 < r1) ? lsig2(B1.x) : 0.f;
        g1[3] = (j0 + 3 < r1) ? lsig2(B1.y) : 0.f;

        g0[2] += g0[3]; g0[1] += g0[2]; g0[0] += g0[1];
        g1[2] += g1[3]; g1[1] += g1[2]; g1[0] += g1[1];
        const float t0 = g0[0], t1 = g1[0];
        float s0 = t0, s1 = t1;
        #pragma unroll
        for (int off = 1; off < 64; off <<= 1) {
            float v0 = __shfl_down(s0, off, 64);
            float v1 = __shfl_down(s1, off, 64);
            if (lane + off < 64) { s0 += v0; s1 += v1; }
        }
        const float base0 = s0 - t0;
        const float base1 = s1 - t1;
        carry0 = __builtin_amdgcn_readfirstlane(s0);
        carry1 = __builtin_amdgcn_readfirstlane(s1);

        f4 gv0 = {g0[0], g0[1], g0[2], g0[3]};
        f4 gv1 = {g1[0], g1[1], g1[2], g1[3]};
        f4 ov0 = (gv0 + base0) * LN2;
        f4 ov1 = (gv1 + base1) * LN2;
        __builtin_nontemporal_store(ov0, (f4*)(o0 + j0));
        __builtin_nontemporal_store(ov1, (f4*)(o1 + j0));
    }

    // ---- interior chunks: unmasked, descending, prefetch next --------------
    for (int cc = cb - 1; cc >= 0; --cc) {
        const int j0 = cc * 256 + 4 * lane;

        f2 A0 = (f2)(0.f), B0 = (f2)(0.f), A1 = (f2)(0.f), B1 = (f2)(0.f);
        #pragma unroll
        for (int d = 0; d < 8; ++d) {
            A0 = __builtin_elementwise_fma(kv[d].xy, q0s[d], A0);
            B0 = __builtin_elementwise_fma(kv[d].zw, q0s[d], B0);
            A1 = __builtin_elementwise_fma(kv[d].xy, q1s[d], A1);
            B1 = __builtin_elementwise_fma(kv[d].zw, q1s[d], B1);
        }

        // kv dead -> issue next chunk's loads (clamped at 0)
        {
            const int cn = (cc > 0) ? (cc - 1) : 0;
            const float* kn = kh + (size_t)cn * (DH * 256);
            #pragma unroll
            for (int d = 0; d < 8; ++d) kv[d] = *(const f4*)(kn + d * 256);
        }

        float g0[4], g1[4];
        g0[0] = lsig2(A0.x); g0[1] = lsig2(A0.y);
        g0[2] = lsig2(B0.x); g0[3] = lsig2(B0.y);
        g1[0] = lsig2(A1.x); g1[1] = lsig2(A1.y);
        g1[2] = lsig2(B1.x); g1[3] = lsig2(B1.y);

        g0[2] += g0[3]; g0[1] += g0[2]; g0[0] += g0[1];
        g1[2] += g1[3]; g1[1] += g1[2]; g1[0] += g1[1];
        const float t0 = g0[0], t1 = g1[0];
        float s0 = t0, s1 = t1;
        #pragma unroll
        for (int off = 1; off < 64; off <<= 1) {
            float v0 = __shfl_down(s0, off, 64);
            float v1 = __shfl_down(s1, off, 64);
            if (lane + off < 64) { s0 += v0; s1 += v1; }
        }
        const float base0 = (s0 - t0) + carry0;
        const float base1 = (s1 - t1) + carry1;
        carry0 += __builtin_amdgcn_readfirstlane(s0);
        carry1 += __builtin_amdgcn_readfirstlane(s1);

        f4 gv0 = {g0[0], g0[1], g0[2], g0[3]};
        f4 gv1 = {g1[0], g1[1], g1[2], g1[3]};
        f4 ov0 = (gv0 + base0) * LN2;
        f4 ov1 = (gv1 + base1) * LN2;
        __builtin_nontemporal_store(ov0, (f4*)(o0 + j0));
        __builtin_nontemporal_store(ov1, (f4*)(o1 + j0));
    }
}

extern "C" void kernel_launch(void* const* d_in, const int* in_sizes, int n_in,
                              void* d_out, int out_size, void* d_ws, size_t ws_size,
                              hipStream_t stream) {
    const float* x = (const float*)d_in[0];
    const float* W = (const float*)d_in[1];
    float* out = (float*)d_out;
    float* qk  = (float*)d_ws;               // 3 MB scratch

    hipLaunchKernelGGL(k_zero, dim3(16, 64, 12), dim3(256), 0, stream, out);
    hipLaunchKernelGGL(k1_proj, dim3(NTOK / 8), dim3(256), 0, stream, x, W, qk);
    hipLaunchKernelGGL(k2_gates, dim3(HEADS * NTOK / 8), dim3(256), 0, stream, qk, out);
}

// Round 9
// 210.456 us; speedup vs baseline: 1.0685x; 1.0685x over previous
//
#include <hip/hip_runtime.h>

#define NTOK 4096
#define DIMC 1024
#define HEADS 12
#define DH 8
#define QSCALE 0.35355339059327373f   /* 8^-0.5 */
#define LOG2E  1.4426950408889634f
#define LN2    0.6931471805599453f
#define QPRE   (QSCALE * LOG2E)       /* fold log2e into q prescale */

typedef float f4 __attribute__((ext_vector_type(4)));
typedef float f2 __attribute__((ext_vector_type(2)));

// ws layout (floats):
//   Q:  [h][n][8]        (pre-scaled by QPRE), offset 0,    12*4096*8
//   K:  [h][16][8][256]  chunk-tiled SoA,      offset KOFF, 12*8*4096
#define KOFF (HEADS * NTOK * DH)

// ---------------- Kernel 1: proj = x @ W^T -> q (AoS, scaled), k (tiled) ---
__global__ __launch_bounds__(256) void k1_proj(const float* __restrict__ x,
                                               const float* __restrict__ W,
                                               float* __restrict__ qk) {
    __shared__ float xs[8 * 1028];         // pad 1024->1028 breaks bank aliasing
    const int t = threadIdx.x;
    const int row0 = blockIdx.x * 8;

    const f4* x4 = (const f4*)(x + (size_t)row0 * DIMC);
    #pragma unroll
    for (int i = 0; i < 8; ++i) {
        int f = t + i * 256;
        int r = f >> 8;
        int c4 = f & 255;
        f4 v = x4[f];
        *(f4*)(&xs[r * 1028 + c4 * 4]) = v;
    }
    __syncthreads();

    const int g  = t >> 2;                 // 0..63 -> owns o = 3g..3g+2
    const int rg = t & 3;                  // owns rows rg*2 .. rg*2+1

    f2 acc[2][3];
    #pragma unroll
    for (int a = 0; a < 2; ++a)
        #pragma unroll
        for (int m = 0; m < 3; ++m) acc[a][m] = (f2)(0.f);

    const float* w0 = W + (size_t)(3 * g) * DIMC;
    #pragma unroll 2
    for (int c = 0; c < DIMC; c += 4) {
        f4 w[3];
        #pragma unroll
        for (int m = 0; m < 3; ++m)
            w[m] = *(const f4*)(w0 + (size_t)m * DIMC + c);
        #pragma unroll
        for (int a = 0; a < 2; ++a) {
            f4 xv = *(const f4*)(&xs[(rg * 2 + a) * 1028 + c]);
            #pragma unroll
            for (int m = 0; m < 3; ++m) {
                acc[a][m] = __builtin_elementwise_fma(xv.xy, w[m].xy, acc[a][m]);
                acc[a][m] = __builtin_elementwise_fma(xv.zw, w[m].zw, acc[a][m]);
            }
        }
    }

    #pragma unroll
    for (int m = 0; m < 3; ++m) {
        int o   = 3 * g + m;
        int qkf = (o >= 96) ? 1 : 0;
        int oo  = o - 96 * qkf;
        int h   = oo >> 3;
        int d   = oo & 7;
        #pragma unroll
        for (int a = 0; a < 2; ++a) {
            int n = row0 + rg * 2 + a;
            float v = acc[a][m].x + acc[a][m].y;
            if (!qkf) {
                qk[((size_t)h * NTOK + n) * DH + d] = v * QPRE;        // Q AoS
            } else {
                qk[KOFF + (((size_t)h * 16 + (n >> 8)) * DH + d) * 256 + (n & 255)] = v;
            }
        }
    }
}

// ---------------- Kernel 2: 2 rows per wave, log2-domain, plain stores -----
__device__ __forceinline__ float lsig2(float u) {
    // logsigmoid in log2 units: min(u,0) - log2(1 + 2^-|u|)   (u = s*log2e)
    float mn = fminf(u, 0.f);
    float z  = __builtin_amdgcn_exp2f(-fabsf(u));   // -|u| is a free modifier
    return mn - __builtin_amdgcn_logf(1.f + z);     // v_log_f32 = log2
}

__global__ __launch_bounds__(256) void k2_gates(const float* __restrict__ qk,
                                                float* __restrict__ out) {
    const int bid  = blockIdx.x;
    const int h    = bid >> 9;              // 512 blocks per head
    const int i0   = (bid & 511) << 3;      // 8 rows per block
    const int t    = threadIdx.x;
    const int lane = t & 63;
    const int wid  = t >> 6;
    const int r0   = i0 + 2 * wid;          // this wave owns rows r0, r0+1
    const int r1   = r0 + 1;

    const float* qrow = qk + ((size_t)h * NTOK + r0) * DH;
    f2 q0s[8], q1s[8];
    #pragma unroll
    for (int d = 0; d < 8; ++d) {
        q0s[d] = (f2)(qrow[d]);
        q1s[d] = (f2)(qrow[DH + d]);
    }

    const float* kh = qk + KOFF + (size_t)h * (16 * DH * 256) + 4 * lane;
    float* o0 = out + ((size_t)h * NTOK + r0) * NTOK;
    float* o1 = o0 + NTOK;

    const int cb = r0 >> 8;                 // boundary chunk (holds j ~ r0)

    // ---- upper-triangle chunks: pure zero stores (plain) -------------------
    f4 z = (f4)(0.f);
    for (int cc = 15; cc > cb; --cc) {
        const int j0 = cc * 256 + 4 * lane;
        *(f4*)(o0 + j0) = z;
        *(f4*)(o1 + j0) = z;
    }

    float carry0, carry1;

    // initial load: boundary chunk
    f4 kv[8];
    {
        const float* kc = kh + (size_t)cb * (DH * 256);
        #pragma unroll
        for (int d = 0; d < 8; ++d) kv[d] = *(const f4*)(kc + d * 256);
    }

    // ---- boundary chunk cc = cb: masked compute, prefetch cb-1 -------------
    {
        const int j0 = cb * 256 + 4 * lane;

        f2 A0 = (f2)(0.f), B0 = (f2)(0.f), A1 = (f2)(0.f), B1 = (f2)(0.f);
        #pragma unroll
        for (int d = 0; d < 8; ++d) {
            A0 = __builtin_elementwise_fma(kv[d].xy, q0s[d], A0);
            B0 = __builtin_elementwise_fma(kv[d].zw, q0s[d], B0);
            A1 = __builtin_elementwise_fma(kv[d].xy, q1s[d], A1);
            B1 = __builtin_elementwise_fma(kv[d].zw, q1s[d], B1);
        }

        // kv dead -> issue next chunk's loads now (clamped), hide under scan
        {
            const int cn = (cb > 0) ? (cb - 1) : 0;
            const float* kn = kh + (size_t)cn * (DH * 256);
            #pragma unroll
            for (int d = 0; d < 8; ++d) kv[d] = *(const f4*)(kn + d * 256);
        }

        float g0[4], g1[4];
        g0[0] = (j0 + 0 < r0) ? lsig2(A0.x) : 0.f;
        g0[1] = (j0 + 1 < r0) ? lsig2(A0.y) : 0.f;
        g0[2] = (j0 + 2 < r0) ? lsig2(B0.x) : 0.f;
        g0[3] = (j0 + 3 < r0) ? lsig2(B0.y) : 0.f;
        g1[0] = (j0 + 0 < r1) ? lsig2(A1.x) : 0.f;
        g1[1] = (j0 + 1 < r1) ? lsig2(A1.y) : 0.f;
        g1[2] = (j0 + 2 < r1) ? lsig2(B1.x) : 0.f;
        g1[3] = (j0 + 3 < r1) ? lsig2(B1.y) : 0.f;

        g0[2] += g0[3]; g0[1] += g0[2]; g0[0] += g0[1];
        g1[2] += g1[3]; g1[1] += g1[2]; g1[0] += g1[1];
        const float t0 = g0[0], t1 = g1[0];
        float s0 = t0, s1 = t1;
        #pragma unroll
        for (int off = 1; off < 64; off <<= 1) {
            float v0 = __shfl_down(s0, off, 64);
            float v1 = __shfl_down(s1, off, 64);
            if (lane + off < 64) { s0 += v0; s1 += v1; }
        }
        const float base0 = s0 - t0;
        const float base1 = s1 - t1;
        carry0 = __builtin_amdgcn_readfirstlane(s0);
        carry1 = __builtin_amdgcn_readfirstlane(s1);

        f4 gv0 = {g0[0], g0[1], g0[2], g0[3]};
        f4 gv1 = {g1[0], g1[1], g1[2], g1[3]};
        *(f4*)(o0 + j0) = (gv0 + base0) * LN2;
        *(f4*)(o1 + j0) = (gv1 + base1) * LN2;
    }

    // ---- interior chunks: unmasked, descending, prefetch next --------------
    for (int cc = cb - 1; cc >= 0; --cc) {
        const int j0 = cc * 256 + 4 * lane;

        f2 A0 = (f2)(0.f), B0 = (f2)(0.f), A1 = (f2)(0.f), B1 = (f2)(0.f);
        #pragma unroll
        for (int d = 0; d < 8; ++d) {
            A0 = __builtin_elementwise_fma(kv[d].xy, q0s[d], A0);
            B0 = __builtin_elementwise_fma(kv[d].zw, q0s[d], B0);
            A1 = __builtin_elementwise_fma(kv[d].xy, q1s[d], A1);
            B1 = __builtin_elementwise_fma(kv[d].zw, q1s[d], B1);
        }

        // kv dead -> issue next chunk's loads (clamped at 0)
        {
            const int cn = (cc > 0) ? (cc - 1) : 0;
            const float* kn = kh + (size_t)cn * (DH * 256);
            #pragma unroll
            for (int d = 0; d < 8; ++d) kv[d] = *(const f4*)(kn + d * 256);
        }

        float g0[4], g1[4];
        g0[0] = lsig2(A0.x); g0[1] = lsig2(A0.y);
        g0[2] = lsig2(B0.x); g0[3] = lsig2(B0.y);
        g1[0] = lsig2(A1.x); g1[1] = lsig2(A1.y);
        g1[2] = lsig2(B1.x); g1[3] = lsig2(B1.y);

        g0[2] += g0[3]; g0[1] += g0[2]; g0[0] += g0[1];
        g1[2] += g1[3]; g1[1] += g1[2]; g1[0] += g1[1];
        const float t0 = g0[0], t1 = g1[0];
        float s0 = t0, s1 = t1;
        #pragma unroll
        for (int off = 1; off < 64; off <<= 1) {
            float v0 = __shfl_down(s0, off, 64);
            float v1 = __shfl_down(s1, off, 64);
            if (lane + off < 64) { s0 += v0; s1 += v1; }
        }
        const float base0 = (s0 - t0) + carry0;
        const float base1 = (s1 - t1) + carry1;
        carry0 += __builtin_amdgcn_readfirstlane(s0);
        carry1 += __builtin_amdgcn_readfirstlane(s1);

        f4 gv0 = {g0[0], g0[1], g0[2], g0[3]};
        f4 gv1 = {g1[0], g1[1], g1[2], g1[3]};
        *(f4*)(o0 + j0) = (gv0 + base0) * LN2;
        *(f4*)(o1 + j0) = (gv1 + base1) * LN2;
    }
}

extern "C" void kernel_launch(void* const* d_in, const int* in_sizes, int n_in,
                              void* d_out, int out_size, void* d_ws, size_t ws_size,
                              hipStream_t stream) {
    const float* x = (const float*)d_in[0];
    const float* W = (const float*)d_in[1];
    float* out = (float*)d_out;
    float* qk  = (float*)d_ws;               // 3 MB scratch

    hipLaunchKernelGGL(k1_proj, dim3(NTOK / 8), dim3(256), 0, stream, x, W, qk);
    hipLaunchKernelGGL(k2_gates, dim3(HEADS * NTOK / 8), dim3(256), 0, stream, qk, out);
}

// Round 10
// 201.228 us; speedup vs baseline: 1.1175x; 1.0459x over previous
//
#include <hip/hip_runtime.h>

#define NTOK 4096
#define DIMC 1024
#define HEADS 12
#define DH 8
#define QSCALE 0.35355339059327373f   /* 8^-0.5 */
#define LOG2E  1.4426950408889634f
#define LN2    0.6931471805599453f
#define QPRE   (QSCALE * LOG2E)       /* fold log2e into q prescale */

typedef float f4 __attribute__((ext_vector_type(4)));
typedef float f2 __attribute__((ext_vector_type(2)));

// ws layout (floats):
//   Q:  [h][n][8]        (pre-scaled by QPRE), offset 0,    12*4096*8
//   K:  [h][16][8][256]  chunk-tiled SoA,      offset KOFF, 12*8*4096
#define KOFF (HEADS * NTOK * DH)

// ---------------- Kernel 1: proj = x @ W^T -> q (AoS, scaled), k (tiled) ---
__global__ __launch_bounds__(256) void k1_proj(const float* __restrict__ x,
                                               const float* __restrict__ W,
                                               float* __restrict__ qk) {
    __shared__ float xs[8 * 1028];         // pad 1024->1028 breaks bank aliasing
    const int t = threadIdx.x;
    const int row0 = blockIdx.x * 8;

    const f4* x4 = (const f4*)(x + (size_t)row0 * DIMC);
    #pragma unroll
    for (int i = 0; i < 8; ++i) {
        int f = t + i * 256;
        int r = f >> 8;
        int c4 = f & 255;
        f4 v = x4[f];
        *(f4*)(&xs[r * 1028 + c4 * 4]) = v;
    }
    __syncthreads();

    const int g  = t >> 2;                 // 0..63 -> owns o = 3g..3g+2
    const int rg = t & 3;                  // owns rows rg*2 .. rg*2+1

    f2 acc[2][3];
    #pragma unroll
    for (int a = 0; a < 2; ++a)
        #pragma unroll
        for (int m = 0; m < 3; ++m) acc[a][m] = (f2)(0.f);

    const float* w0 = W + (size_t)(3 * g) * DIMC;
    #pragma unroll 2
    for (int c = 0; c < DIMC; c += 4) {
        f4 w[3];
        #pragma unroll
        for (int m = 0; m < 3; ++m)
            w[m] = *(const f4*)(w0 + (size_t)m * DIMC + c);
        #pragma unroll
        for (int a = 0; a < 2; ++a) {
            f4 xv = *(const f4*)(&xs[(rg * 2 + a) * 1028 + c]);
            #pragma unroll
            for (int m = 0; m < 3; ++m) {
                acc[a][m] = __builtin_elementwise_fma(xv.xy, w[m].xy, acc[a][m]);
                acc[a][m] = __builtin_elementwise_fma(xv.zw, w[m].zw, acc[a][m]);
            }
        }
    }

    #pragma unroll
    for (int m = 0; m < 3; ++m) {
        int o   = 3 * g + m;
        int qkf = (o >= 96) ? 1 : 0;
        int oo  = o - 96 * qkf;
        int h   = oo >> 3;
        int d   = oo & 7;
        #pragma unroll
        for (int a = 0; a < 2; ++a) {
            int n = row0 + rg * 2 + a;
            float v = acc[a][m].x + acc[a][m].y;
            if (!qkf) {
                qk[((size_t)h * NTOK + n) * DH + d] = v * QPRE;        // Q AoS
            } else {
                qk[KOFF + (((size_t)h * 16 + (n >> 8)) * DH + d) * 256 + (n & 255)] = v;
            }
        }
    }
}

// ---------------- Kernel 2: 1 contiguous row per wave, LDS-staged K --------
__device__ __forceinline__ float lsig2(float u) {
    // logsigmoid in log2 units: min(u,0) - log2(1 + 2^-|u|)   (u = s*log2e)
    float mn = fminf(u, 0.f);
    float z  = __builtin_amdgcn_exp2f(-fabsf(u));   // -|u| is a free modifier
    return mn - __builtin_amdgcn_logf(1.f + z);     // v_log_f32 = log2
}

__global__ __launch_bounds__(256) void k2_gates(const float* __restrict__ qk,
                                                float* __restrict__ out) {
    const int bid  = blockIdx.x;
    const int h    = bid >> 10;             // 1024 blocks per head
    const int r0   = (bid & 1023) << 2;     // 4 rows per block, 1 per wave
    const int t    = threadIdx.x;
    const int lane = t & 63;
    const int w    = t >> 6;
    const int r    = r0 + w;                // this wave's row

    __shared__ float ks[2][8 * 256];        // double-buffered K chunk (2 x 8 KB)

    // q row (wave-uniform)
    const float* qp = qk + ((size_t)h * NTOK + r) * DH;
    float qs[8];
    #pragma unroll
    for (int d = 0; d < 8; ++d) qs[d] = qp[d];

    float* o = out + ((size_t)h * NTOK + r) * NTOK;
    const int cb = r0 >> 8;                 // boundary chunk (same for all 4 rows)
    const int rm = r & 255;                 // row offset within boundary chunk

    // ---- strictly-upper chunks: zero stores, linear walk per row ----------
    f4 z = (f4)(0.f);
    for (int cc = 15; cc > cb; --cc)
        __builtin_nontemporal_store(z, (f4*)(o + cc * 256 + 4 * lane));

    // ---- prologue: stage chunk cb into ks[0] ------------------------------
    {
        const float* kt = qk + KOFF + ((size_t)h * 16 + cb) * 2048;
        f4 a = *(const f4*)(kt + 4 * t);
        f4 b = *(const f4*)(kt + 4 * t + 1024);
        *(f4*)(&ks[0][4 * t]) = a;
        *(f4*)(&ks[0][4 * t + 1024]) = b;
    }
    __syncthreads();

    float carry = 0.f;
    int p = 0;

    for (int c = cb; c >= 0; --c) {
        // issue next chunk's global loads early (clamped at 0)
        const int cn = (c > 0) ? (c - 1) : 0;
        const float* kt = qk + KOFF + ((size_t)h * 16 + cn) * 2048;
        f4 sa = *(const f4*)(kt + 4 * t);
        f4 sb = *(const f4*)(kt + 4 * t + 1024);

        // compute this chunk from LDS (all 4 waves share the tile)
        f4 kv[8];
        #pragma unroll
        for (int d = 0; d < 8; ++d)
            kv[d] = *(const f4*)(&ks[p][d * 256 + 4 * lane]);

        f2 A = (f2)(0.f), B = (f2)(0.f);
        #pragma unroll
        for (int d = 0; d < 8; ++d) {
            A = __builtin_elementwise_fma(kv[d].xy, (f2)(qs[d]), A);
            B = __builtin_elementwise_fma(kv[d].zw, (f2)(qs[d]), B);
        }

        float g[4];
        if (c == cb) {                       // boundary: mask j < r
            g[0] = (4 * lane + 0 < rm) ? lsig2(A.x) : 0.f;
            g[1] = (4 * lane + 1 < rm) ? lsig2(A.y) : 0.f;
            g[2] = (4 * lane + 2 < rm) ? lsig2(B.x) : 0.f;
            g[3] = (4 * lane + 3 < rm) ? lsig2(B.y) : 0.f;
        } else {                             // interior: all j < r
            g[0] = lsig2(A.x); g[1] = lsig2(A.y);
            g[2] = lsig2(B.x); g[3] = lsig2(B.y);
        }

        g[2] += g[3]; g[1] += g[2]; g[0] += g[1];   // local reverse suffix
        const float tot = g[0];
        float s = tot;
        #pragma unroll
        for (int off = 1; off < 64; off <<= 1) {
            float v = __shfl_down(s, off, 64);
            if (lane + off < 64) s += v;
        }
        const float base = (s - tot) + carry;
        carry += __builtin_amdgcn_readfirstlane(s);

        f4 gv = {g[0], g[1], g[2], g[3]};
        __builtin_nontemporal_store((gv + base) * LN2, (f4*)(o + c * 256 + 4 * lane));

        // write staged regs into the other LDS buffer, flip
        *(f4*)(&ks[p ^ 1][4 * t]) = sa;
        *(f4*)(&ks[p ^ 1][4 * t + 1024]) = sb;
        __syncthreads();
        p ^= 1;
    }
}

extern "C" void kernel_launch(void* const* d_in, const int* in_sizes, int n_in,
                              void* d_out, int out_size, void* d_ws, size_t ws_size,
                              hipStream_t stream) {
    const float* x = (const float*)d_in[0];
    const float* W = (const float*)d_in[1];
    float* out = (float*)d_out;
    float* qk  = (float*)d_ws;               // 3 MB scratch

    hipLaunchKernelGGL(k1_proj, dim3(NTOK / 8), dim3(256), 0, stream, x, W, qk);
    hipLaunchKernelGGL(k2_gates, dim3(HEADS * NTOK / 4), dim3(256), 0, stream, qk, out);
}